// Round 7
// baseline (157.471 us; speedup 1.0000x reference)
//
#include <hip/hip_runtime.h>
#include <hip/hip_bf16.h>

#define B_   64
#define NW_  256
#define H_   768

#define AB_    (0.1f / 768.0f)   // ALPHA*BETA
#define OMB_   0.9f              // 1 - BETA
#define K1_    0.1f
#define BP_    1.2f
#define AVDL_  50.0f

typedef __bf16 bf16x8 __attribute__((ext_vector_type(8)));
typedef float  f32x4  __attribute__((ext_vector_type(4)));
typedef float  f32x8  __attribute__((ext_vector_type(8)));

// Direct global->LDS DMA, 16 B per lane. Dest = wave-uniform base + lane*16.
__device__ __forceinline__ void load_lds16(const float* g, float* l) {
    __builtin_amdgcn_global_load_lds(
        (const __attribute__((address_space(1))) void*)g,
        (__attribute__((address_space(3))) void*)l, 16, 0, 0);
}

// Barrier with explicit VMEM depth N: waits lgkmcnt(0) (own LDS reads done)
// and vmcnt(N) (all but the N newest DMA loads complete) — never a full
// drain in steady state. This is the AITER-style fine-grained pipeline.
#define WBAR(N) asm volatile("s_waitcnt vmcnt(" #N ") lgkmcnt(0)\n\ts_barrier" ::: "memory")

// ---------------------------------------------------------------------------
// 128x128-tile GEMM, fused score epilogue; DMA-staged quad-buffered K-loop.
// Grid: 256 blocks of 256 threads; bid = t*64 + b -> XCD = b%8 (batch's
// slice L2-resident). Wave w computes quadrant (qm=w>>1, qn=w&1), full K.
// K-loop: 24 chunks of BK=32 f32, staged via global_load_lds into a 4-deep
// LDS ring; per iter: read frags (cvt f32->bf16 in VALU) -> MFMA ->
// WBAR(16) -> DMA chunk kc+4 into freed buffer. vmcnt never drains to 0
// until the tail. XOR swizzle (16B segs ^ (row&3)<<1) at the global-address
// level keeps frag reads at 4-way conflicts despite the pad-free layout.
// ---------------------------------------------------------------------------
__global__ __launch_bounds__(256, 1) void gemm_fused(
    const float* __restrict__ q_rep, const float* __restrict__ d_rep,
    const int* __restrict__ q_ids, const int* __restrict__ d_ids,
    const int* __restrict__ d_tfs,
    float* __restrict__ S, float* __restrict__ ws_etdf)
{
    extern __shared__ __align__(16) char smem[];
    float* ASb    = (float*)smem;             // [4][128][32] f32 = 64 KB
    float* BSb    = (float*)(smem + 65536);   // [4][128][32] f32 = 64 KB
    int4*  qk_s   = (int4*) (smem + 131072);  // 128 q id keys
    int4*  dk_s   = (int4*) (smem + 133120);  // 128 d id keys
    float* mq_s   = (float*)(smem + 135168);
    float* md_s   = (float*)(smem + 135680);
    float* mdtf_s = (float*)(smem + 136192);
    float* tf_s   = (float*)(smem + 136704);  // end 137216

    const int tid  = threadIdx.x;
    const int wave = tid >> 6;
    const int lane = tid & 63;
    const int bid  = blockIdx.x;
    const int b    = bid & 63;
    const int t    = bid >> 6;          // tile 0..3
    const int m0   = (t & 1) * 128;
    const int n0   = (t >> 1) * 128;

    // Side data into LDS, then one full-drain sync (once; vmcnt=0 after).
    if (tid < 128) {
        int4 qa = *(const int4*)(q_ids + ((size_t)b * NW_ + m0 + tid) * 4);
        qk_s[tid] = qa;
        mq_s[tid] = (qa.x == 0 && qa.y == 0 && qa.z == 0 && qa.w == 0) ? 0.f : 1.f;
    } else {
        const int r = tid - 128;
        int4 da = *(const int4*)(d_ids + ((size_t)b * NW_ + n0 + r) * 4);
        dk_s[r] = da;
        float md = (da.x == 0 && da.y == 0 && da.z == 0 && da.w == 0) ? 0.f : 1.f;
        float tf = (float)d_tfs[(size_t)b * NW_ + n0 + r];
        md_s[r]   = md;
        tf_s[r]   = tf;
        mdtf_s[r] = md * tf;
    }
    __syncthreads();

    // DMA staging geometry: one instr = 64 lanes x 16 B = 8 rows x 128 B.
    // Lane: row-in-group = lane>>3, 16B slot = lane&7. Swizzle: the slot
    // holds global k-segment (slot ^ ((row&3)<<1)); row&3 == (lane>>3)&3.
    const int srow = lane >> 3;                       // 0..7
    const int kslot = (lane & 7) ^ ((srow & 3) << 1); // global 16B seg to fetch
    const float* pa[4];
    const float* pb[4];
#pragma unroll
    for (int i = 0; i < 4; ++i) {
        const int row = wave * 32 + i * 8 + srow;
        pa[i] = q_rep + ((size_t)b * NW_ + m0 + row) * H_ + kslot * 4;
        pb[i] = d_rep + ((size_t)b * NW_ + n0 + row) * H_ + kslot * 4;
    }

    auto issue = [&](int buf) {       // DMA one 128x32-f32 chunk pair -> ring[buf]
        float* A = ASb + buf * 4096;
        float* Bl = BSb + buf * 4096;
#pragma unroll
        for (int i = 0; i < 4; ++i) {
            load_lds16(pa[i], A  + (wave * 32 + i * 8) * 32);
            load_lds16(pb[i], Bl + (wave * 32 + i * 8) * 32);
        }
#pragma unroll
        for (int i = 0; i < 4; ++i) { pa[i] += 32; pb[i] += 32; }
    };

    f32x4 acc[4][4];
#pragma unroll
    for (int i = 0; i < 4; ++i)
#pragma unroll
        for (int j = 0; j < 4; ++j)
            acc[i][j] = (f32x4){0.f, 0.f, 0.f, 0.f};

    const int fr = lane & 15;
    const int qg = lane >> 4;
    const int qm = wave >> 1;           // quadrant row
    const int qn = wave & 1;            // quadrant col
    // Frag-read word offset: k words [qg*8, qg*8+8) live at stored 16B segs
    // {2qg^m, 2qg^m+1}, m=(fr&3)<<1 -> words 8*(qg^(fr&3)).
    const int fwoff = 8 * (qg ^ (fr & 3));

    auto compute = [&](int buf) {
        const float* A = ASb + buf * 4096;
        const float* Bl = BSb + buf * 4096;
        bf16x8 af[4], bfr[4];
#pragma unroll
        for (int t4 = 0; t4 < 4; ++t4) {
            f32x8 va = *(const f32x8*)(A + (qm * 64 + t4 * 16 + fr) * 32 + fwoff);
            f32x8 vb = *(const f32x8*)(Bl + (qn * 64 + t4 * 16 + fr) * 32 + fwoff);
#pragma unroll
            for (int e = 0; e < 8; ++e) {
                af[t4][e]  = (__bf16)va[e];
                bfr[t4][e] = (__bf16)vb[e];
            }
        }
#pragma unroll
        for (int i = 0; i < 4; ++i)
#pragma unroll
            for (int j = 0; j < 4; ++j)
                acc[i][j] = __builtin_amdgcn_mfma_f32_16x16x32_bf16(
                    af[i], bfr[j], acc[i][j], 0, 0, 0);
    };

    // Prologue: 4 chunks in flight; wait until chunk 0 resident (vmcnt 24 =
    // 3 chunks x 8 instrs may remain outstanding).
    issue(0); issue(1); issue(2); issue(3);
    WBAR(24);

    // Steady state: read kc, guarantee kc+1 (vmcnt 16 leaves kc+2,kc+3 in
    // flight across the barrier), refill ring[kc%4] with chunk kc+4.
#pragma unroll
    for (int kc = 0; kc < 20; ++kc) {
        const int buf = kc & 3;
        compute(buf);
        WBAR(16);
        issue(buf);
    }
    // Tail: no more issues; step the depth down. 20 needs 21 done (16 ok),
    // 21 needs 22 (8), 22 needs 23 (0), 23 reads last.
    compute(0); WBAR(16);
    compute(1); WBAR(8);
    compute(2); WBAR(0);
    compute(3);

    // Epilogue. C layout: col = lane&15, row = (lane>>4)*4 + reg.
    const int cn = lane & 15;
    float md_l[4], mdtf_l[4], tf_l[4];
    int4  dk_l[4];
#pragma unroll
    for (int j = 0; j < 4; ++j) {
        const int c = qn * 64 + j * 16 + cn;
        md_l[j]   = md_s[c];
        mdtf_l[j] = mdtf_s[c];
        tf_l[j]   = tf_s[c];
        dk_l[j]   = dk_s[c];
    }
    float* Sbase = S + ((size_t)b * NW_ + m0 + qm * 64) * NW_ + n0 + qn * 64;

    float rs[16];
#pragma unroll
    for (int i = 0; i < 4; ++i)
#pragma unroll
        for (int r = 0; r < 4; ++r) {
            const int row = i * 16 + qg * 4 + r;
            const float mq = mq_s[qm * 64 + row];
            const int4  qk = qk_s[qm * 64 + row];
            float sdot = 0.f, sem = 0.f;
#pragma unroll
            for (int j = 0; j < 4; ++j) {
                const float v = acc[i][j][r];
                Sbase[(size_t)row * NW_ + j * 16 + cn] = v * mq * md_l[j];
                sdot += v * mdtf_l[j];
                const int4 dk = dk_l[j];
                if (dk.x == qk.x && dk.y == qk.y && dk.z == qk.z && dk.w == qk.w)
                    sem += tf_l[j];
            }
            rs[i * 4 + r] = mq * AB_ * sdot + OMB_ * sem;
        }
#pragma unroll
    for (int off = 1; off <= 8; off <<= 1)
#pragma unroll
        for (int e = 0; e < 16; ++e)
            rs[e] += __shfl_xor(rs[e], off);
    if (cn == 0) {
#pragma unroll
        for (int i = 0; i < 4; ++i)
#pragma unroll
            for (int r = 0; r < 4; ++r)
                atomicAdd(&ws_etdf[(size_t)b * NW_ + m0 + qm * 64 + i * 16 + qg * 4 + r],
                          rs[i * 4 + r]);
    }
}

// ---------------------------------------------------------------------------
// Final: per batch, dl = sum(tf); dtw = 1.1*etdf/(etdf + K1*(1-Bp+Bp*dl/AVDL)
// + 1e-8); s[b] = sum_q qtw*dtw.  One wave per batch.
// ---------------------------------------------------------------------------
__global__ __launch_bounds__(64) void final_kernel(
    const float* __restrict__ ws_etdf, const int* __restrict__ d_tfs,
    const float* __restrict__ qtw, float* __restrict__ out)
{
    const int b = blockIdx.x;
    const int lane = threadIdx.x;

    float4 ev = *(const float4*)(ws_etdf + (size_t)b * NW_ + lane * 4);
    int4  tf4 = *(const int4*)(d_tfs   + (size_t)b * NW_ + lane * 4);
    float4 qv = *(const float4*)(qtw    + (size_t)b * NW_ + lane * 4);

    float dl = (float)(tf4.x + tf4.y + tf4.z + tf4.w);
#pragma unroll
    for (int off = 32; off; off >>= 1) dl += __shfl_xor(dl, off);

    const float c = K1_ * (1.f - BP_ + BP_ * dl / AVDL_);
    float ew[4] = {ev.x, ev.y, ev.z, ev.w};
    float qw[4] = {qv.x, qv.y, qv.z, qv.w};
    float s = 0.f;
#pragma unroll
    for (int j = 0; j < 4; ++j)
        s += qw[j] * (ew[j] * (1.f + K1_)) / (ew[j] + c + 1e-8f);
#pragma unroll
    for (int off = 32; off; off >>= 1) s += __shfl_xor(s, off);
    if (lane == 0) out[b] = s;
}

extern "C" void kernel_launch(void* const* d_in, const int* in_sizes, int n_in,
                              void* d_out, int out_size, void* d_ws, size_t ws_size,
                              hipStream_t stream)
{
    const float* q_rep = (const float*)d_in[0];
    const float* d_rep = (const float*)d_in[1];
    const float* qtw   = (const float*)d_in[2];
    const int*   q_ids = (const int*)d_in[3];
    const int*   d_ids = (const int*)d_in[4];
    const int*   d_tfs = (const int*)d_in[5];

    float* out = (float*)d_out;
    float* S   = out + B_;              // d_expanded_tf, [B, NW, NW]
    float* ws_etdf = (float*)d_ws;      // [B, NW] f32

    hipFuncSetAttribute((const void*)gemm_fused,
                        hipFuncAttributeMaxDynamicSharedMemorySize, 137216);

    hipMemsetAsync(ws_etdf, 0, (size_t)B_ * NW_ * sizeof(float), stream);

    gemm_fused<<<256, 256, 137216, stream>>>(q_rep, d_rep, q_ids, d_ids, d_tfs,
                                             S, ws_etdf);
    final_kernel<<<B_, 64, 0, stream>>>(ws_etdf, d_tfs, qtw, out);
}